// Round 5
// baseline (1286.421 us; speedup 1.0000x reference)
//
#include <hip/hip_runtime.h>
#include <hip/hip_bf16.h>
#include <stdint.h>
#include <stddef.h>

typedef __bf16 bf16_t;
typedef __bf16 bf16x8 __attribute__((ext_vector_type(8)));
typedef float  f32x4  __attribute__((ext_vector_type(4)));

#define MFMA16(a, b, c) __builtin_amdgcn_mfma_f32_16x16x32_bf16((a), (b), (c), 0, 0, 0)
// Per-wave DS-queue drain: enforces same-wave LDS RAW/WAR ordering between
// phases without any cross-wave barrier (whole main loop is wave-private).
#define LGKM0() asm volatile("s_waitcnt lgkmcnt(0)" ::: "memory")

// SiLU with raw v_rcp_f32 (1-ulp; invisible after bf16 truncation).
__device__ __forceinline__ float silu_f(float v) {
    return v * __builtin_amdgcn_rcpf(1.f + __expf(-v));
}

namespace cfg {
constexpr int B    = 131072;
constexpr int DIM  = 40;
constexpr int H    = 128;
constexpr int AD   = 20;
constexpr int L    = 6;
constexpr int MB   = 64;     // rows per block
constexpr int NTH  = 256;    // threads per block (4 waves; each wave owns 16 rows)
constexpr int ZS   = 41;     // z_s padded stride (41 coprime 32 banks)

// uniform transposed-weight tiles: [L][21][128][32] bf16 (64-B rows, line-aligned)
//   tiles 0..8  = W1 K-tiles (K padded 288)
//   tiles 9..12 = W2, 13..16 = W3, 17..20 = [Ws|Wt] (cols 0..19 s, 32..51 t)
constexpr int TILE = 128 * 32;      // 4096 elems / 8192 B
constexpr int LSTR = 21 * TILE;     // per-layer stride
constexpr int WTOT = 6 * LSTR;      // 516096 elems

constexpr int CTE_BLKS = (B / 16) * 512 / 256;  // 16384 cte-prep blocks
constexpr int W_BLKS   = WTOT / 256;            // 2016 weight-prep blocks
}

// Static module-scope staging; rewritten by prep kernel every launch.
__device__ bf16_t g_wsb[cfg::WTOT];
// physical-slot tables: pa[6][32] (k 20..31 padded w/ slot 0), pb[6][20], fout[40]
__device__ int    g_gtab[352];
// ctx|te bf16, swizzled to mm1 A-frag order: [B/16][kt 8][lane 64][8 elems]
// -> lane's 16-B A-frag load is perfectly coalesced (1 KB/wave/instruction).
__device__ bf16_t g_cte[(size_t)cfg::B * 256];

// ---------------------------------------------------------------------------
// prep_all: one launch. Blocks [0,CTE_BLKS): cte fp32 -> swizzled bf16.
// Blocks [CTE_BLKS, +W_BLKS): fp32 weights -> bf16 transposed tiles [n][k32];
// first w-block also composes the permutation algebra into slot tables.
// ---------------------------------------------------------------------------
__global__ void prep_all(const float* __restrict__ ctx, const float* __restrict__ te,
                         const float* __restrict__ W1, const float* __restrict__ W2,
                         const float* __restrict__ W3, const float* __restrict__ Ws,
                         const float* __restrict__ Wt, const int* __restrict__ perm,
                         const int* __restrict__ ia, const int* __restrict__ ib)
{
    using namespace cfg;
    __shared__ int phys_s[40], tmp_s[40], pas[20], pbs[20];

    if (blockIdx.x < CTE_BLKS) {
        // one 16-B output chunk per thread
        size_t o16 = (size_t)blockIdx.x * 256 + threadIdx.x;
        int g16 = (int)(o16 >> 9);
        int r   = (int)(o16 & 511);
        int kt  = r >> 6, ln = r & 63;
        int row  = g16 * 16 + (ln & 15);
        int col0 = kt * 32 + (ln >> 4) * 8;
        const float* src = (col0 < 128) ? &ctx[(size_t)row * 128 + col0]
                                        : &te[(size_t)row * 128 + (col0 - 128)];
        float4 v0 = *(const float4*)src;
        float4 v1 = *(const float4*)(src + 4);
        bf16x8 bv;
        bv[0] = (bf16_t)v0.x; bv[1] = (bf16_t)v0.y; bv[2] = (bf16_t)v0.z; bv[3] = (bf16_t)v0.w;
        bv[4] = (bf16_t)v1.x; bv[5] = (bf16_t)v1.y; bv[6] = (bf16_t)v1.z; bv[7] = (bf16_t)v1.w;
        *(bf16x8*)&g_cte[o16 * 8] = bv;
        return;
    }

    int bb = blockIdx.x - CTE_BLKS;
    int t  = bb * 256 + threadIdx.x;            // < WTOT
    {
        int i = t / LSTR, r = t % LSTR;
        int tile = r / TILE, r2 = r % TILE;
        int n = r2 >> 5, kl = r2 & 31;
        float v = 0.f;
        if (tile < 9) {                      // W1: h0 k-layout [za(20) pad12 | ctx | te]
            int k = tile * 32 + kl;
            if (k < 20)       v = W1[(i * 276 + k) * 128 + n];
            else if (k >= 32) v = W1[(i * 276 + (k - 12)) * 128 + n];
        } else if (tile < 13) {
            int k = (tile - 9) * 32 + kl;
            v = W2[(i * 128 + k) * 128 + n];
        } else if (tile < 17) {
            int k = (tile - 13) * 32 + kl;
            v = W3[(i * 128 + k) * 128 + n];
        } else {
            int k = (tile - 17) * 32 + kl;
            if (n < 20)                 v = Ws[(i * 128 + k) * 20 + n];
            else if (n >= 32 && n < 52) v = Wt[(i * 128 + k) * 20 + (n - 32)];
        }
        g_wsb[t] = (bf16_t)v;
    }

    if (bb == 0) {
        int u = threadIdx.x;
        if (u < 40) phys_s[u] = u;
        __syncthreads();
        for (int i = 0; i < L; ++i) {
            if (u < 20) {
                int sa = phys_s[perm[i * 40 + ia[i * 20 + u]]];
                int sb = phys_s[perm[i * 40 + ib[i * 20 + u]]];
                pas[u] = sa; pbs[u] = sb;
                g_gtab[i * 32 + u]        = sa;
                g_gtab[192 + i * 20 + u]  = sb;
            } else if (u < 32) {
                g_gtab[i * 32 + u] = 0;          // benign pad slot (weights are 0 there)
            }
            __syncthreads();
            if (u < 20) {
                tmp_s[ia[i * 20 + u]] = pas[u];
                tmp_s[ib[i * 20 + u]] = pbs[u];
            }
            __syncthreads();
            if (u < 40) phys_s[u] = tmp_s[u];
            __syncthreads();
        }
        if (u < 40) g_gtab[312 + u] = phys_s[u];
    }
}

// ---------------------------------------------------------------------------
// In-place dense mm on the wave's OWN 16 rows x 128 cols:
//   h[rw..rw+15][0..127] = SiLU(h @ W + b).
// All 4 A-frags loaded before any write; every write data-depends on every
// read (acc accumulates over all kt) -> in-place is hazard-free, no barrier.
// ---------------------------------------------------------------------------
__device__ __forceinline__ void mm_inplace(
    bf16_t* h, const bf16_t* __restrict__ wl, const float* __restrict__ bias,
    int q, int c, int rw)
{
    using namespace cfg;
    bf16x8 af[4];
    #pragma unroll
    for (int kt = 0; kt < 4; ++kt)
        af[kt] = *(const bf16x8*)&h[(rw + c) * 136 + kt * 32 + q * 8];
    f32x4 acc[8] = {};
    __builtin_amdgcn_s_setprio(1);
    #pragma unroll
    for (int kt = 0; kt < 4; ++kt) {
        #pragma unroll
        for (int nt = 0; nt < 8; ++nt) {
            int an = (nt >> 1) * 32 + 2 * c + (nt & 1);   // paired cols -> b32 stores
            bf16x8 bfr = *(const bf16x8*)&wl[kt * TILE + an * 32 + q * 8];
            acc[nt] = MFMA16(af[kt], bfr, acc[nt]);
        }
    }
    __builtin_amdgcn_s_setprio(0);
    #pragma unroll
    for (int g = 0; g < 4; ++g) {
        int n0 = g * 32 + 2 * c;
        float bv0 = bias[n0], bv1 = bias[n0 + 1];
        #pragma unroll
        for (int rr = 0; rr < 4; ++rr) {
            float v0 = silu_f(acc[2 * g][rr] + bv0);
            float v1 = silu_f(acc[2 * g + 1][rr] + bv1);
            union { bf16_t h2[2]; uint32_t u32; } pk;
            pk.h2[0] = (bf16_t)v0; pk.h2[1] = (bf16_t)v1;
            *(uint32_t*)&h[(rw + q * 4 + rr) * 136 + n0] = pk.u32;
        }
    }
}

__global__ __launch_bounds__(256, 4) void flow_main(
    const float* __restrict__ x,
    const float* __restrict__ b1, const float* __restrict__ b2, const float* __restrict__ b3,
    const float* __restrict__ bs, const float* __restrict__ bt,
    float* __restrict__ out)
{
    using namespace cfg;
    // LDS: 29312 B -> 5 blocks/CU (LDS-wise). Single h buffer (in-place mms).
    __shared__ __align__(16) char smem[29312];
    float*  z_s  = (float*)(smem);             // [64][41] f32   @0      (10496 B)
    bf16_t* h    = (bf16_t*)(smem + 10496);    // [64][136] bf16 @10496  (17408 B)
    int*    gtab = (int*)(smem + 27904);       // 352 ints       @27904  (1408 B)

    const int tid  = threadIdx.x;
    const int lane = tid & 63;
    const int w    = tid >> 6;
    const int q    = lane >> 4, c = lane & 15;
    const int rw   = w * 16;                   // this wave owns rows rw..rw+15
    const int row0 = blockIdx.x * MB;
    const int g16  = blockIdx.x * 4 + w;       // cte group for this wave

    for (int e = tid; e < 352; e += NTH) gtab[e] = g_gtab[e];
    for (int e = tid; e < MB * DIM; e += NTH) {
        int r = e / DIM, d = e - r * DIM;
        z_s[r * ZS + d] = x[(size_t)row0 * DIM + e];
    }
    float ld[4] = {0.f, 0.f, 0.f, 0.f};
    __syncthreads();                           // the ONLY block barrier

    for (int i = 0; i < L; ++i) {
        const bf16_t* wlay = g_wsb + i * LSTR;
        const int* pa = gtab + i * 32;          // za read slots (padded to 32)
        const int* pb = gtab + 192 + i * 20;    // zb read/write slots

        // ---- mm1: [za | cte] @ W1t -> SiLU -> h (own 16 rows, all 128 cols)
        {
            f32x4 acc[8] = {};
            {   // K-tile 0: inline z_a gather; k>=20 lanes read benign slot 0
                // against zeroed weight columns.
                bf16x8 af;
                #pragma unroll
                for (int j = 0; j < 8; ++j)
                    af[j] = (bf16_t)z_s[(rw + c) * ZS + pa[q * 8 + j]];
                #pragma unroll
                for (int nt = 0; nt < 8; ++nt) {
                    int an = (nt >> 1) * 32 + 2 * c + (nt & 1);
                    bf16x8 bfr = *(const bf16x8*)&wlay[an * 32 + q * 8];
                    acc[nt] = MFMA16(af, bfr, acc[nt]);
                }
            }
            __builtin_amdgcn_s_setprio(1);
            #pragma unroll
            for (int kt = 1; kt < 9; ++kt) {   // ctx/te: coalesced swizzled loads
                bf16x8 af = *(const bf16x8*)&g_cte[(size_t)g16 * 4096 + (kt - 1) * 512 + lane * 8];
                #pragma unroll
                for (int nt = 0; nt < 8; ++nt) {
                    int an = (nt >> 1) * 32 + 2 * c + (nt & 1);
                    bf16x8 bfr = *(const bf16x8*)&wlay[kt * TILE + an * 32 + q * 8];
                    acc[nt] = MFMA16(af, bfr, acc[nt]);
                }
            }
            __builtin_amdgcn_s_setprio(0);
            const float* bias = b1 + i * H;
            #pragma unroll
            for (int g = 0; g < 4; ++g) {
                int n0 = g * 32 + 2 * c;
                float bv0 = bias[n0], bv1 = bias[n0 + 1];
                #pragma unroll
                for (int rr = 0; rr < 4; ++rr) {
                    float v0 = silu_f(acc[2 * g][rr] + bv0);
                    float v1 = silu_f(acc[2 * g + 1][rr] + bv1);
                    union { bf16_t h2[2]; uint32_t u32; } pk;
                    pk.h2[0] = (bf16_t)v0; pk.h2[1] = (bf16_t)v1;
                    *(uint32_t*)&h[(rw + q * 4 + rr) * 136 + n0] = pk.u32;
                }
            }
        }
        LGKM0();                               // h writes ordered before mm2 reads

        mm_inplace(h, wlay + 9 * TILE,  b2 + i * H, q, c, rw);
        LGKM0();
        mm_inplace(h, wlay + 13 * TILE, b3 + i * H, q, c, rw);
        LGKM0();

        // ---- fused st + epilogue, fully in-register (own 16 rows).
        {
            const bf16_t* wst = wlay + 17 * TILE;
            f32x4 acc[4] = {};
            __builtin_amdgcn_s_setprio(1);
            #pragma unroll
            for (int kt = 0; kt < 4; ++kt) {
                bf16x8 af = *(const bf16x8*)&h[(rw + c) * 136 + kt * 32 + q * 8];
                #pragma unroll
                for (int nt = 0; nt < 4; ++nt) {
                    bf16x8 bfr = *(const bf16x8*)&wst[kt * TILE + (nt * 16 + c) * 32 + q * 8];
                    acc[nt] = MFMA16(af, bfr, acc[nt]);
                }
            }
            __builtin_amdgcn_s_setprio(0);
            float bs0 = bs[i * AD + c];
            float bt0 = bt[i * AD + c];
            int   sl1 = pb[c];
            float bs1 = 0.f, bt1 = 0.f; int sl2 = 0;
            if (c < 4) { bs1 = bs[i * AD + 16 + c]; bt1 = bt[i * AD + 16 + c]; sl2 = pb[16 + c]; }
            #pragma unroll
            for (int rr = 0; rr < 4; ++rr) {
                int row = rw + q * 4 + rr;
                float s1 = fminf(fmaxf(acc[0][rr] + bs0, -2.f), 2.f);
                float y1 = z_s[row * ZS + sl1] * __expf(s1) + (acc[2][rr] + bt0);
                z_s[row * ZS + sl1] = y1;
                float ssum = s1;
                if (c < 4) {
                    float s2 = fminf(fmaxf(acc[1][rr] + bs1, -2.f), 2.f);
                    float y2 = z_s[row * ZS + sl2] * __expf(s2) + (acc[3][rr] + bt1);
                    z_s[row * ZS + sl2] = y2;
                    ssum += s2;
                }
                // row-sum of s across the 16 c-lanes (same q group)
                ssum += __shfl_xor(ssum, 1);
                ssum += __shfl_xor(ssum, 2);
                ssum += __shfl_xor(ssum, 4);
                ssum += __shfl_xor(ssum, 8);
                ld[rr] += ssum;
            }
        }
        LGKM0();                               // z_s stable for next layer (own wave)
    }

    // out gather through the final physical-slot map — wave-private rows.
    const int* fo = gtab + 312;
    for (int k = lane; k < 16 * DIM; k += 64) {
        int r = k / DIM, d = k - r * DIM;
        out[(size_t)(row0 + rw) * DIM + k] = z_s[(rw + r) * ZS + fo[d]];
    }
    if (c == 0) {
        #pragma unroll
        for (int rr = 0; rr < 4; ++rr)
            out[(size_t)B * DIM + row0 + rw + q * 4 + rr] = ld[rr];
    }
}

extern "C" void kernel_launch(void* const* d_in, const int* in_sizes, int n_in,
                              void* d_out, int out_size, void* d_ws, size_t ws_size,
                              hipStream_t stream) {
    using namespace cfg;
    const float* x   = (const float*)d_in[0];
    const float* ctx = (const float*)d_in[1];
    const float* te  = (const float*)d_in[2];
    const float* W1  = (const float*)d_in[3];
    const float* b1  = (const float*)d_in[4];
    const float* W2  = (const float*)d_in[5];
    const float* b2  = (const float*)d_in[6];
    const float* W3  = (const float*)d_in[7];
    const float* b3  = (const float*)d_in[8];
    const float* Ws_ = (const float*)d_in[9];
    const float* bs_ = (const float*)d_in[10];
    const float* Wt_ = (const float*)d_in[11];
    const float* bt_ = (const float*)d_in[12];
    const int* perm  = (const int*)d_in[13];
    const int* ia    = (const int*)d_in[14];
    const int* ib    = (const int*)d_in[15];

    float* out = (float*)d_out;

    prep_all<<<CTE_BLKS + W_BLKS, 256, 0, stream>>>(ctx, te, W1, W2, W3, Ws_, Wt_, perm, ia, ib);
    flow_main<<<B / MB, NTH, 0, stream>>>(x, b1, b2, b3, bs_, bt_, out);
}

// Round 6
// 469.378 us; speedup vs baseline: 2.7407x; 2.7407x over previous
//
#include <hip/hip_runtime.h>
#include <hip/hip_bf16.h>
#include <stdint.h>
#include <stddef.h>

typedef __bf16 bf16_t;
typedef __bf16 bf16x8 __attribute__((ext_vector_type(8)));
typedef float  f32x4  __attribute__((ext_vector_type(4)));

#define MFMA16(a, b, c) __builtin_amdgcn_mfma_f32_16x16x32_bf16((a), (b), (c), 0, 0, 0)

// SiLU with raw v_rcp_f32 (1-ulp; invisible after bf16 truncation).
__device__ __forceinline__ float silu_f(float v) {
    return v * __builtin_amdgcn_rcpf(1.f + __expf(-v));
}

namespace cfg {
constexpr int B    = 131072;
constexpr int DIM  = 40;
constexpr int H    = 128;
constexpr int AD   = 20;
constexpr int L    = 6;
constexpr int MB   = 64;     // rows per block
constexpr int NTH  = 256;    // threads per block (4 waves)
constexpr int ZS   = 41;     // z_s padded stride

// uniform transposed-weight tiles: [L][21][128][32] bf16 (64-B rows)
//   tiles 0..8 = W1 (K padded 288); 9..12 = W2; 13..16 = W3; 17..20 = [Ws|Wt]
constexpr int TILE = 128 * 32;      // 4096 elems / 8192 B
constexpr int LSTR = 21 * TILE;
constexpr int WTOT = 6 * LSTR;
constexpr int NPH  = 6 * 21;        // 126 staged tile-phases

constexpr int CTE_BLKS = (B / 16) * 512 / 256;
constexpr int W_BLKS   = WTOT / 256;
}

__device__ __align__(16) bf16_t g_wsb[cfg::WTOT];
// slot tables: pa[6][32] (k 20..31 pad slot 0), pb[6][20], fout[40]
__device__ int    g_gtab[352];
// ctx|te bf16 swizzled [B/16][kt 8][lane 64][8] for coalesced mm1 A-frag loads
__device__ __align__(16) bf16_t g_cte[(size_t)cfg::B * 256];

// LDS weight-tile element offset for (col an, k-group s): slot-XOR breaks the
// 16-way bank conflict of linear [128][64B] column reads (G4/m201 pattern).
__device__ __forceinline__ int woff(int an, int s) {
    return an * 32 + ((s ^ ((an >> 1) & 3)) << 3);
}

// ---------------------------------------------------------------------------
// prep_all (unchanged from round 5; passed correctness)
// ---------------------------------------------------------------------------
__global__ void prep_all(const float* __restrict__ ctx, const float* __restrict__ te,
                         const float* __restrict__ W1, const float* __restrict__ W2,
                         const float* __restrict__ W3, const float* __restrict__ Ws,
                         const float* __restrict__ Wt, const int* __restrict__ perm,
                         const int* __restrict__ ia, const int* __restrict__ ib)
{
    using namespace cfg;
    __shared__ int phys_s[40], tmp_s[40], pas[20], pbs[20];

    if (blockIdx.x < CTE_BLKS) {
        size_t o16 = (size_t)blockIdx.x * 256 + threadIdx.x;
        int g16 = (int)(o16 >> 9);
        int r   = (int)(o16 & 511);
        int kt  = r >> 6, ln = r & 63;
        int row  = g16 * 16 + (ln & 15);
        int col0 = kt * 32 + (ln >> 4) * 8;
        const float* src = (col0 < 128) ? &ctx[(size_t)row * 128 + col0]
                                        : &te[(size_t)row * 128 + (col0 - 128)];
        float4 v0 = *(const float4*)src;
        float4 v1 = *(const float4*)(src + 4);
        bf16x8 bv;
        bv[0] = (bf16_t)v0.x; bv[1] = (bf16_t)v0.y; bv[2] = (bf16_t)v0.z; bv[3] = (bf16_t)v0.w;
        bv[4] = (bf16_t)v1.x; bv[5] = (bf16_t)v1.y; bv[6] = (bf16_t)v1.z; bv[7] = (bf16_t)v1.w;
        *(bf16x8*)&g_cte[o16 * 8] = bv;
        return;
    }

    int bb = blockIdx.x - CTE_BLKS;
    int t  = bb * 256 + threadIdx.x;
    {
        int i = t / LSTR, r = t % LSTR;
        int tile = r / TILE, r2 = r % TILE;
        int n = r2 >> 5, kl = r2 & 31;
        float v = 0.f;
        if (tile < 9) {
            int k = tile * 32 + kl;
            if (k < 20)       v = W1[(i * 276 + k) * 128 + n];
            else if (k >= 32) v = W1[(i * 276 + (k - 12)) * 128 + n];
        } else if (tile < 13) {
            int k = (tile - 9) * 32 + kl;
            v = W2[(i * 128 + k) * 128 + n];
        } else if (tile < 17) {
            int k = (tile - 13) * 32 + kl;
            v = W3[(i * 128 + k) * 128 + n];
        } else {
            int k = (tile - 17) * 32 + kl;
            if (n < 20)                 v = Ws[(i * 128 + k) * 20 + n];
            else if (n >= 32 && n < 52) v = Wt[(i * 128 + k) * 20 + (n - 32)];
        }
        g_wsb[t] = (bf16_t)v;
    }

    if (bb == 0) {
        int u = threadIdx.x;
        if (u < 40) phys_s[u] = u;
        __syncthreads();
        for (int i = 0; i < L; ++i) {
            if (u < 20) {
                int sa = phys_s[perm[i * 40 + ia[i * 20 + u]]];
                int sb = phys_s[perm[i * 40 + ib[i * 20 + u]]];
                pas[u] = sa; pbs[u] = sb;
                g_gtab[i * 32 + u]        = sa;
                g_gtab[192 + i * 20 + u]  = sb;
            } else if (u < 32) {
                g_gtab[i * 32 + u] = 0;
            }
            __syncthreads();
            if (u < 20) {
                tmp_s[ia[i * 20 + u]] = pas[u];
                tmp_s[ib[i * 20 + u]] = pbs[u];
            }
            __syncthreads();
            if (u < 40) phys_s[u] = tmp_s[u];
            __syncthreads();
        }
        if (u < 40) g_gtab[312 + u] = phys_s[u];
    }
}

// ---------------------------------------------------------------------------
// flow_main: 126 staged phases. Per phase: issue global loads for tile T+1,
// compute tile T from LDS, ds_write staged regs, __syncthreads.
// Dense mms: wave w owns cols [w*32,+32) x all 64 rows; h updated in place
// (A-frags hoisted at each mm's first phase; >=1 barrier before any h-write).
// st: wave owns 16 rows; in-register s/t epilogue updates z_s slots in place.
// ---------------------------------------------------------------------------
__global__ __launch_bounds__(256, 3) void flow_main(
    const float* __restrict__ x,
    const float* __restrict__ gb1, const float* __restrict__ gb2, const float* __restrict__ gb3,
    const float* __restrict__ gbs, const float* __restrict__ gbt,
    float* __restrict__ out)
{
    using namespace cfg;
    // LDS 45696 B -> 3 blocks/CU
    __shared__ __align__(16) char smem[45696];
    float*  z_s  = (float*)(smem);             // [64][41] f32   @0      (10496 B)
    bf16_t* h    = (bf16_t*)(smem + 10496);    // [64][136] bf16 @10496  (17408 B)
    bf16_t* wb   = (bf16_t*)(smem + 27904);    // [2][128][32]   @27904  (16384 B)
    int*    gtab = (int*)(smem + 44288);       // 352 ints       @44288  (1408 B)

    const int tid  = threadIdx.x;
    const int lane = tid & 63;
    const int w    = tid >> 6;
    const int q    = lane >> 4, c = lane & 15;
    const int rw   = w * 16;                   // st row base
    const int cb   = w * 32 + 2 * c;           // dense-mm col-pair base
    const int row0 = blockIdx.x * MB;

    for (int e = tid; e < 352; e += NTH) gtab[e] = g_gtab[e];
    for (int e = tid; e < MB * DIM; e += NTH) {
        int r = e / DIM, d = e - r * DIM;
        z_s[r * ZS + d] = x[(size_t)row0 * DIM + e];
    }

    uint4 sg0, sg1;
    const int an0 = tid >> 2, sl0 = tid & 3;
    auto SLOAD = [&](int T) {
        const bf16_t* s = g_wsb + (size_t)T * TILE;
        sg0 = *(const uint4*)(s + tid * 8);
        sg1 = *(const uint4*)(s + 2048 + tid * 8);
    };
    auto SWRITE = [&](bf16_t* wbc) {
        *(uint4*)&wbc[woff(an0, sl0)]      = sg0;
        *(uint4*)&wbc[woff(an0 + 64, sl0)] = sg1;
    };

    SLOAD(0);
    SWRITE(wb);
    float ld[4] = {0.f, 0.f, 0.f, 0.f};
    __syncthreads();
    int cur = 0;

    for (int i = 0; i < L; ++i) {
        const int* pa = gtab + i * 32;
        const int* pb = gtab + 192 + i * 20;
        const int  T0 = i * 21;

        // ---- mm1: phases 0..8 (tiles T0..T0+8)
        {
            f32x4 acc[4][2] = {};
            bf16x8 aN[4];
            #pragma unroll
            for (int kt = 0; kt < 9; ++kt) {
                bf16_t* wbc = wb + cur * 4096;
                SLOAD(T0 + kt + 1);
                bf16x8 aK[4];
                if (kt == 0) {
                    #pragma unroll
                    for (int rf = 0; rf < 4; ++rf) {
                        bf16x8 t;
                        #pragma unroll
                        for (int j = 0; j < 8; ++j)
                            t[j] = (bf16_t)z_s[(rf * 16 + c) * ZS + pa[q * 8 + j]];
                        aK[rf] = t;
                    }
                    #pragma unroll
                    for (int rf = 0; rf < 4; ++rf)   // prefetch cte kt=1 (storage 0)
                        aN[rf] = *(const bf16x8*)&g_cte[((size_t)(blockIdx.x * 4 + rf)) * 4096 + lane * 8];
                } else {
                    #pragma unroll
                    for (int rf = 0; rf < 4; ++rf) aK[rf] = aN[rf];
                    if (kt < 8) {
                        #pragma unroll
                        for (int rf = 0; rf < 4; ++rf)  // prefetch cte kt+1 (storage kt)
                            aN[rf] = *(const bf16x8*)&g_cte[((size_t)(blockIdx.x * 4 + rf)) * 4096 + (size_t)kt * 512 + lane * 8];
                    }
                }
                bf16x8 b0 = *(const bf16x8*)&wbc[woff(cb, q)];
                bf16x8 b1 = *(const bf16x8*)&wbc[woff(cb + 1, q)];
                __builtin_amdgcn_s_setprio(1);
                #pragma unroll
                for (int rf = 0; rf < 4; ++rf) {
                    acc[rf][0] = MFMA16(aK[rf], b0, acc[rf][0]);
                    acc[rf][1] = MFMA16(aK[rf], b1, acc[rf][1]);
                }
                __builtin_amdgcn_s_setprio(0);
                if (kt == 8) {                       // SiLU epilogue -> h
                    float bv0 = gb1[i * H + cb], bv1 = gb1[i * H + cb + 1];
                    #pragma unroll
                    for (int rf = 0; rf < 4; ++rf)
                        #pragma unroll
                        for (int rr = 0; rr < 4; ++rr) {
                            float v0 = silu_f(acc[rf][0][rr] + bv0);
                            float v1 = silu_f(acc[rf][1][rr] + bv1);
                            union { bf16_t h2[2]; uint32_t u; } pk;
                            pk.h2[0] = (bf16_t)v0; pk.h2[1] = (bf16_t)v1;
                            *(uint32_t*)&h[(rf * 16 + q * 4 + rr) * 136 + cb] = pk.u;
                        }
                }
                SWRITE(wb + (cur ^ 1) * 4096);
                __syncthreads();
                cur ^= 1;
            }
        }

        // ---- mm2 (phases 9..12), mm3 (13..16): in-place h, hoisted A
        #pragma unroll
        for (int mm = 0; mm < 2; ++mm) {
            bf16x8 ah[16];
            #pragma unroll
            for (int kt = 0; kt < 4; ++kt)
                #pragma unroll
                for (int rf = 0; rf < 4; ++rf)
                    ah[kt * 4 + rf] = *(const bf16x8*)&h[(rf * 16 + c) * 136 + kt * 32 + q * 8];
            f32x4 acc[4][2] = {};
            const float* bias = (mm == 0 ? gb2 : gb3) + i * H;
            #pragma unroll
            for (int kt = 0; kt < 4; ++kt) {
                bf16_t* wbc = wb + cur * 4096;
                SLOAD(T0 + 9 + mm * 4 + kt + 1);
                bf16x8 b0 = *(const bf16x8*)&wbc[woff(cb, q)];
                bf16x8 b1 = *(const bf16x8*)&wbc[woff(cb + 1, q)];
                __builtin_amdgcn_s_setprio(1);
                #pragma unroll
                for (int rf = 0; rf < 4; ++rf) {
                    acc[rf][0] = MFMA16(ah[kt * 4 + rf], b0, acc[rf][0]);
                    acc[rf][1] = MFMA16(ah[kt * 4 + rf], b1, acc[rf][1]);
                }
                __builtin_amdgcn_s_setprio(0);
                if (kt == 3) {
                    float bv0 = bias[cb], bv1 = bias[cb + 1];
                    #pragma unroll
                    for (int rf = 0; rf < 4; ++rf)
                        #pragma unroll
                        for (int rr = 0; rr < 4; ++rr) {
                            float v0 = silu_f(acc[rf][0][rr] + bv0);
                            float v1 = silu_f(acc[rf][1][rr] + bv1);
                            union { bf16_t h2[2]; uint32_t u; } pk;
                            pk.h2[0] = (bf16_t)v0; pk.h2[1] = (bf16_t)v1;
                            *(uint32_t*)&h[(rf * 16 + q * 4 + rr) * 136 + cb] = pk.u;
                        }
                }
                SWRITE(wb + (cur ^ 1) * 4096);
                __syncthreads();
                cur ^= 1;
            }
        }

        // ---- st (phases 17..20) + fused epilogue (wave-private 16 rows)
        {
            f32x4 sacc[4] = {};
            #pragma unroll
            for (int kt = 0; kt < 4; ++kt) {
                bf16_t* wbc = wb + cur * 4096;
                int Tn = T0 + 18 + kt;
                if (Tn < NPH) SLOAD(Tn);
                bf16x8 af = *(const bf16x8*)&h[(rw + c) * 136 + kt * 32 + q * 8];
                __builtin_amdgcn_s_setprio(1);
                #pragma unroll
                for (int nt = 0; nt < 4; ++nt) {
                    bf16x8 bfr = *(const bf16x8*)&wbc[woff(nt * 16 + c, q)];
                    sacc[nt] = MFMA16(af, bfr, sacc[nt]);
                }
                __builtin_amdgcn_s_setprio(0);
                if (kt == 3) {
                    float bs0 = gbs[i * AD + c];
                    float bt0 = gbt[i * AD + c];
                    int   sl1 = pb[c];
                    float bs1 = 0.f, bt1 = 0.f; int sl2 = 0;
                    if (c < 4) { bs1 = gbs[i * AD + 16 + c]; bt1 = gbt[i * AD + 16 + c]; sl2 = pb[16 + c]; }
                    #pragma unroll
                    for (int rr = 0; rr < 4; ++rr) {
                        int row = rw + q * 4 + rr;
                        float s1 = fminf(fmaxf(sacc[0][rr] + bs0, -2.f), 2.f);
                        float y1 = z_s[row * ZS + sl1] * __expf(s1) + (sacc[2][rr] + bt0);
                        z_s[row * ZS + sl1] = y1;
                        float ssum = s1;
                        if (c < 4) {
                            float s2 = fminf(fmaxf(sacc[1][rr] + bs1, -2.f), 2.f);
                            float y2 = z_s[row * ZS + sl2] * __expf(s2) + (sacc[3][rr] + bt1);
                            z_s[row * ZS + sl2] = y2;
                            ssum += s2;
                        }
                        ssum += __shfl_xor(ssum, 1);
                        ssum += __shfl_xor(ssum, 2);
                        ssum += __shfl_xor(ssum, 4);
                        ssum += __shfl_xor(ssum, 8);
                        ld[rr] += ssum;
                    }
                }
                if (Tn < NPH) SWRITE(wb + (cur ^ 1) * 4096);
                __syncthreads();
                cur ^= 1;
            }
        }
    }

    // out gather through the final physical-slot map — wave-private rows.
    const int* fo = gtab + 312;
    for (int k = lane; k < 16 * DIM; k += 64) {
        int r = k / DIM, d = k - r * DIM;
        out[(size_t)(row0 + rw) * DIM + k] = z_s[(rw + r) * ZS + fo[d]];
    }
    if (c == 0) {
        #pragma unroll
        for (int rr = 0; rr < 4; ++rr)
            out[(size_t)B * DIM + row0 + rw + q * 4 + rr] = ld[rr];
    }
}

extern "C" void kernel_launch(void* const* d_in, const int* in_sizes, int n_in,
                              void* d_out, int out_size, void* d_ws, size_t ws_size,
                              hipStream_t stream) {
    using namespace cfg;
    const float* x   = (const float*)d_in[0];
    const float* ctx = (const float*)d_in[1];
    const float* te  = (const float*)d_in[2];
    const float* W1  = (const float*)d_in[3];
    const float* b1  = (const float*)d_in[4];
    const float* W2  = (const float*)d_in[5];
    const float* b2  = (const float*)d_in[6];
    const float* W3  = (const float*)d_in[7];
    const float* b3  = (const float*)d_in[8];
    const float* Ws_ = (const float*)d_in[9];
    const float* bs_ = (const float*)d_in[10];
    const float* Wt_ = (const float*)d_in[11];
    const float* bt_ = (const float*)d_in[12];
    const int* perm  = (const int*)d_in[13];
    const int* ia    = (const int*)d_in[14];
    const int* ib    = (const int*)d_in[15];

    float* out = (float*)d_out;

    prep_all<<<CTE_BLKS + W_BLKS, 256, 0, stream>>>(ctx, te, W1, W2, W3, Ws_, Wt_, perm, ia, ib);
    flow_main<<<B / MB, NTH, 0, stream>>>(x, b1, b2, b3, bs_, bt_, out);
}